// Round 6
// baseline (168.829 us; speedup 1.0000x reference)
//
#include <hip/hip_runtime.h>
#include <stdint.h>

// Geometry (fixed): B=4, C=512, H=W=64
#define NB 4
#define CB 512
#define HH 64
#define WW 64
#define HW 4096
#define C4 2048
#define PTOT (NB*HW)   // 16384 pixels across batch

typedef float  f32x4  __attribute__((ext_vector_type(4)));
typedef short  bf16x8 __attribute__((ext_vector_type(8)));

__device__ __forceinline__ float relu_f(float v){ return v > 0.f ? v : 0.f; }

__device__ __forceinline__ float bf2f(unsigned short u){
    union { uint32_t i; float f; } v; v.i = ((uint32_t)u) << 16; return v.f;
}
__device__ __forceinline__ unsigned short f2bf(float f){
    union { float f; uint32_t i; } v; v.f = f;
    uint32_t r = v.i + 0x7FFFu + ((v.i >> 16) & 1u);   // RNE
    return (unsigned short)(r >> 16);
}

__device__ __forceinline__ void gload16(const void* g, void* l){
    __builtin_amdgcn_global_load_lds(
        (const __attribute__((address_space(1))) uint32_t*)g,
        (__attribute__((address_space(3))) uint32_t*)l, 16, 0, 0);
}

// ---------------------------------------------------------------------------
// fp32 -> bf16 cast of the three weight matrices in one launch.
// ---------------------------------------------------------------------------
__global__ __launch_bounds__(256) void cast3_f32_bf16(
    const float* __restrict__ a, unsigned short* __restrict__ oa,
    const float* __restrict__ b, unsigned short* __restrict__ ob,
    const float* __restrict__ c, unsigned short* __restrict__ oc)
{
    int i = blockIdx.x * 256 + threadIdx.x;
    const float* src; unsigned short* dst; int j;
    if (i < 65536)        { src = a; dst = oa; j = i; }
    else if (i < 327680)  { src = b; dst = ob; j = i - 65536; }
    else                  { src = c; dst = oc; j = i - 327680; }
    float4 v = ((const float4*)src)[j];
    ushort4 o;
    o.x = f2bf(v.x); o.y = f2bf(v.y); o.z = f2bf(v.z); o.w = f2bf(v.w);
    ((ushort4*)dst)[j] = o;
}

// ---------------------------------------------------------------------------
// x [b][c][p] fp32  ->  xT [b*HW + p][c] bf16   (64x64 LDS tile transpose)
// ---------------------------------------------------------------------------
__global__ __launch_bounds__(256) void transpose_cast_x(
    const float* __restrict__ x, unsigned short* __restrict__ xT)
{
    __shared__ unsigned short tile[64][72];
    const int b  = blockIdx.z;
    const int p0 = blockIdx.x * 64;
    const int c0 = blockIdx.y * 64;
    const int t  = threadIdx.x;

    const int pl = (t & 15) * 4;
    const int cl = t >> 4;
    const float* src = x + ((size_t)b * CB + c0) * HW + p0;
    #pragma unroll
    for (int r = 0; r < 4; r++) {
        int c = cl + r * 16;
        float4 v = *(const float4*)(src + (size_t)c * HW + pl);
        tile[pl + 0][c] = f2bf(v.x);
        tile[pl + 1][c] = f2bf(v.y);
        tile[pl + 2][c] = f2bf(v.z);
        tile[pl + 3][c] = f2bf(v.w);
    }
    __syncthreads();
    unsigned short* dst = xT + ((size_t)b * HW + p0) * CB + c0;
    const int cl2 = (t & 15) * 4;
    const int pl2 = t >> 4;
    #pragma unroll
    for (int r = 0; r < 4; r++) {
        int p = pl2 + r * 16;
        ushort4 o = *(ushort4*)&tile[p][cl2];
        *(ushort4*)(dst + (size_t)p * CB + cl2) = o;
    }
}

// ---------------------------------------------------------------------------
// Channel-last MFMA GEMM, 4-phase/K-tile schedule (T3+T4+T5), triple-buffer:
//   D[p][o] = sum_k A[p][k] * Bw[o][k]  (bf16 in, f32 acc)
// BM=256 x BN=128, BK=64, 8 waves (512 thr), grid (64,4) = 256 blocks = 1/CU.
// LDS: 3 buffers x (A 32K | B 16K) = 144K dynamic -> 1 block/CU.
// Depth-2 prefetch: computing tile t (cur), t+1 resident (nxt), t+2 (fut)
// loads issued across t's phases. Per-tile wait = vmcnt(6), never 0 in loop.
// NOTE: __launch_bounds__(512) with NO min-waves arg — R5's (512,2) clamped
// VGPRs to 64 and spilled the 64-reg accumulator to scratch (+130MB writes).
// OUTMODE 0: bf16 [PTOT][512] channel-last; 1: fp32 [b][512][HW] + ReLU.
// ---------------------------------------------------------------------------
template<int K, int OUTMODE>
__global__ __launch_bounds__(512) void gemm_cl(
    const unsigned short* __restrict__ A,
    const unsigned short* __restrict__ Bw,
    void* __restrict__ out)
{
    extern __shared__ __align__(16) char lds[];

    const int t    = threadIdx.x;
    const int lane = t & 63;
    const int wid  = t >> 6;          // 0..7
    const int p0   = blockIdx.x * 256;
    const int o0   = blockIdx.y * 128;

    const int l15 = lane & 15;
    const int l4  = lane >> 4;        // 0..3
    const int m0  = (wid >> 1) * 64;  // wave p-offset (0,64,128,192)
    const int n0  = (wid & 1) * 64;   // wave o-offset (0,64)
    const int swz = (l15 & 7) << 4;   // read-side XOR (row&7)<<4

    f32x4 acc[4][4];
    #pragma unroll
    for (int m = 0; m < 4; m++)
        #pragma unroll
        for (int n = 0; n < 4; n++) acc[m][n] = (f32x4)0.f;

    // staging decode: per chunk (128 rows x 128B = 16KB), 2 loads/thread
    const int sr  = lane >> 3;        // 0..7  == row&7 (swizzle row bits)
    const int scb = (lane & 7) * 16;  // byte col of granule
    const int skk = (scb ^ (sr << 4)) >> 1;   // pre-swizzled source k-elem off

    auto STAGE_A = [&](int k0, int half, char* buf) {
        #pragma unroll
        for (int j = 0; j < 2; ++j) {
            const int r = half * 128 + j * 64 + wid * 8 + sr;
            gload16(A + (size_t)(p0 + r) * K + k0 + skk,
                    buf + half * 16384 + j * 8192 + wid * 1024);
        }
    };
    auto STAGE_B = [&](int k0, char* buf) {
        #pragma unroll
        for (int j = 0; j < 2; ++j) {
            const int r = j * 64 + wid * 8 + sr;
            gload16(Bw + (size_t)(o0 + r) * K + k0 + skk,
                    buf + 32768 + j * 8192 + wid * 1024);
        }
    };

    char* buf0 = lds;
    char* buf1 = lds + 49152;
    char* buf2 = lds + 98304;

    // prologue: stage tiles 0 and 1 (12 loads in flight)
    STAGE_A(0, 0, buf0); STAGE_A(0, 1, buf0); STAGE_B(0, buf0);
    STAGE_A(64, 0, buf1); STAGE_A(64, 1, buf1); STAGE_B(64, buf1);

    char* cur = buf0; char* nxt = buf1; char* fut = buf2;
    const int NT = K / 64;

#define PH(khv, mhv, STCODE)                                                   \
    {                                                                          \
        const int colb = (khv) * 64 + l4 * 16;                                 \
        af0 = *(const bf16x8*)(cur + (m0 + (2*(mhv)  )*16 + l15)*128 + (colb ^ swz)); \
        af1 = *(const bf16x8*)(cur + (m0 + (2*(mhv)+1)*16 + l15)*128 + (colb ^ swz)); \
        if ((mhv) == 0) {                                                      \
            _Pragma("unroll")                                                  \
            for (int nn = 0; nn < 4; ++nn)                                     \
                bfr[nn] = *(const bf16x8*)(cur + 32768 +                       \
                           (n0 + nn*16 + l15)*128 + (colb ^ swz));             \
        }                                                                      \
        STCODE;                                                                \
        __builtin_amdgcn_s_barrier();                                          \
        asm volatile("s_waitcnt lgkmcnt(0)" ::: "memory");                     \
        __builtin_amdgcn_sched_barrier(0);                                     \
        __builtin_amdgcn_s_setprio(1);                                         \
        _Pragma("unroll")                                                      \
        for (int nn = 0; nn < 4; ++nn) {                                       \
            acc[2*(mhv)  ][nn] = __builtin_amdgcn_mfma_f32_16x16x32_bf16(      \
                                    af0, bfr[nn], acc[2*(mhv)  ][nn], 0, 0, 0);\
            acc[2*(mhv)+1][nn] = __builtin_amdgcn_mfma_f32_16x16x32_bf16(      \
                                    af1, bfr[nn], acc[2*(mhv)+1][nn], 0, 0, 0);\
        }                                                                      \
        __builtin_amdgcn_s_setprio(0);                                         \
        __builtin_amdgcn_sched_barrier(0);                                     \
        __builtin_amdgcn_s_barrier();                                          \
    }

    for (int tt = 0; tt < NT; ++tt) {
        if (tt < NT - 1) asm volatile("s_waitcnt vmcnt(6)" ::: "memory");
        else             asm volatile("s_waitcnt vmcnt(0)" ::: "memory");
        __builtin_amdgcn_s_barrier();      // tile tt resident in cur everywhere

        const int  k2 = (tt + 2) * 64;
        const bool st = (tt + 2 < NT);
        bf16x8 bfr[4], af0, af1;

        PH(0, 0, { if (st) STAGE_A(k2, 0, fut); })   // phase 0
        PH(0, 1, { if (st) STAGE_A(k2, 1, fut); })   // phase 1
        PH(1, 0, { if (st) STAGE_B(k2, fut);    })   // phase 2
        PH(1, 1, { })                                // phase 3

        char* tmp = cur; cur = nxt; nxt = fut; fut = tmp;
    }
#undef PH

    if (OUTMODE == 0) {
        unsigned short* op = (unsigned short*)out;
        #pragma unroll
        for (int m = 0; m < 4; m++)
            #pragma unroll
            for (int r = 0; r < 4; r++) {
                const int p = p0 + m0 + m * 16 + l4 * 4 + r;
                #pragma unroll
                for (int n = 0; n < 4; n++) {
                    const int o = o0 + n0 + n * 16 + l15;
                    op[(size_t)p * CB + o] = f2bf(acc[m][n][r]);
                }
            }
    } else {
        // fp32 channel-first + ReLU via LDS transpose: tl[128 o][260 p-pad]
        __syncthreads();
        float (*tl)[260] = (float(*)[260])lds;    // 133120 B < 147456
        #pragma unroll
        for (int n = 0; n < 4; n++)
            #pragma unroll
            for (int m = 0; m < 4; m++)
                #pragma unroll
                for (int r = 0; r < 4; r++)
                    tl[n0 + n * 16 + l15][m0 + m * 16 + l4 * 4 + r] = acc[m][n][r];
        __syncthreads();
        const int bb   = p0 >> 12;
        const int phw0 = p0 & (HW - 1);
        const int orow = t >> 2;            // 0..127
        const int pseg = (t & 3) * 64;      // 0..192
        float* dst = (float*)out + ((size_t)(bb * CB + o0 + orow)) * HW + phw0 + pseg;
        #pragma unroll
        for (int j = 0; j < 16; j++) {
            float4 v = *(float4*)&tl[orow][pseg + j * 4];
            v.x = relu_f(v.x); v.y = relu_f(v.y); v.z = relu_f(v.z); v.w = relu_f(v.w);
            *(float4*)(dst + j * 4) = v;
        }
    }
}

// ---------------------------------------------------------------------------
// Fused 4-direction IRNN scan, channel-last, scalar channel per thread.
// grid (512, 4): blockIdx.y = dir (0=u,1=r,2=d,3=l). Depth-8 reg prefetch.
// ---------------------------------------------------------------------------
__global__ __launch_bounds__(256) void irnn_fused(
    const unsigned short* __restrict__ in, unsigned short* __restrict__ outc,
    const float* __restrict__ wu, const float* __restrict__ bu,
    const float* __restrict__ wr, const float* __restrict__ br,
    const float* __restrict__ wd, const float* __restrict__ bd,
    const float* __restrict__ wl, const float* __restrict__ bl)
{
    const int dir = blockIdx.y;
    const float* wv; const float* bv; int pstep, rev;
    if      (dir == 0) { wv = wu; bv = bu; pstep = 64; rev = 1; }  // up
    else if (dir == 1) { wv = wr; bv = br; pstep = 1;  rev = 0; }  // right
    else if (dir == 2) { wv = wd; bv = bd; pstep = 64; rev = 0; }  // down
    else               { wv = wl; bv = bl; pstep = 1;  rev = 1; }  // left
    const int dirOff = dir * 512;

    const int idx = blockIdx.x * 256 + threadIdx.x;  // 0..131071
    const int c = idx & 511;
    const int f = (idx >> 9) & 63;
    const int b = idx >> 15;
    const int fbase = (pstep == 64) ? f : f * 64;

    const float wc = wv[c], bc = bv[c];
    const int t0 = rev ? 63 : 0;
    const int dp = rev ? -pstep : pstep;
    const int istep = dp * CB;
    const int ostep = dp * C4;

    const unsigned short* ip = in   + ((size_t)b * HW + fbase + (size_t)t0 * pstep) * CB + c;
    unsigned short*       op = outc + ((size_t)b * HW + fbase + (size_t)t0 * pstep) * C4 + dirOff + c;

    float s = relu_f(bf2f(ip[0]));
    op[0] = 0;

    unsigned short v0 = ip[1*istep], v1 = ip[2*istep], v2 = ip[3*istep], v3 = ip[4*istep],
                   v4 = ip[5*istep], v5 = ip[6*istep], v6 = ip[7*istep], v7 = ip[8*istep];

#define DO(kk, vv) { s = relu_f(fmaf(s, wc, bc + bf2f(vv))); op[(kk)*ostep] = f2bf(s); }
    for (int g = 0; g < 6; ++g) {
        const int k0 = 1 + 8 * g;
        DO(k0+0, v0); v0 = ip[(k0+ 8)*istep];
        DO(k0+1, v1); v1 = ip[(k0+ 9)*istep];
        DO(k0+2, v2); v2 = ip[(k0+10)*istep];
        DO(k0+3, v3); v3 = ip[(k0+11)*istep];
        DO(k0+4, v4); v4 = ip[(k0+12)*istep];
        DO(k0+5, v5); v5 = ip[(k0+13)*istep];
        DO(k0+6, v6); v6 = ip[(k0+14)*istep];
        DO(k0+7, v7); v7 = ip[(k0+15)*istep];
    }
    DO(49, v0); v0 = ip[57*istep];
    DO(50, v1); v1 = ip[58*istep];
    DO(51, v2); v2 = ip[59*istep];
    DO(52, v3); v3 = ip[60*istep];
    DO(53, v4); v4 = ip[61*istep];
    DO(54, v5); v5 = ip[62*istep];
    DO(55, v6); v6 = ip[63*istep];
    DO(56, v7);
    DO(57, v0); DO(58, v1); DO(59, v2); DO(60, v3);
    DO(61, v4); DO(62, v5); DO(63, v6);
#undef DO
}

// ---------------------------------------------------------------------------
// ws map: [0,16M) xT | [16M,80M) concat_T | [80M,96M) out0/mid |
//         [96M,..) bf16 weights. conv3x3 "attention" branch is dead -> skipped.
// ---------------------------------------------------------------------------
extern "C" void kernel_launch(void* const* d_in, const int* in_sizes, int n_in,
                              void* d_out, int out_size, void* d_ws, size_t ws_size,
                              hipStream_t stream) {
    const float* x     = (const float*)d_in[0];
    const float* cin_w = (const float*)d_in[7];
    const float* c2_w  = (const float*)d_in[8];
    const float* c3_w  = (const float*)d_in[9];
    const float* i1_wu = (const float*)d_in[10];
    const float* i1_bu = (const float*)d_in[11];
    const float* i1_wr = (const float*)d_in[12];
    const float* i1_br = (const float*)d_in[13];
    const float* i1_wd = (const float*)d_in[14];
    const float* i1_bd = (const float*)d_in[15];
    const float* i1_wl = (const float*)d_in[16];
    const float* i1_bl = (const float*)d_in[17];
    const float* i2_wu = (const float*)d_in[18];
    const float* i2_bu = (const float*)d_in[19];
    const float* i2_wr = (const float*)d_in[20];
    const float* i2_br = (const float*)d_in[21];
    const float* i2_wd = (const float*)d_in[22];
    const float* i2_bd = (const float*)d_in[23];
    const float* i2_wl = (const float*)d_in[24];
    const float* i2_bl = (const float*)d_in[25];

    char* ws = (char*)d_ws;
    unsigned short* xT     = (unsigned short*)(ws);
    unsigned short* concat = (unsigned short*)(ws + (size_t)16 * 1024 * 1024);
    unsigned short* mid    = (unsigned short*)(ws + (size_t)80 * 1024 * 1024);
    unsigned short* wA     = (unsigned short*)(ws + (size_t)96 * 1024 * 1024);
    unsigned short* wB     = (unsigned short*)(wA + 512 * 512);
    unsigned short* wC     = (unsigned short*)(wB + 512 * 2048);

    cast3_f32_bf16<<<2304, 256, 0, stream>>>(cin_w, wA, c2_w, wB, c3_w, wC);
    transpose_cast_x<<<dim3(HW/64, CB/64, NB), 256, 0, stream>>>(x, xT);

    dim3 ggrid(PTOT/256, 4);     // 64 x 4 = 256 blocks = 1/CU
    dim3 sgrid(512, 4);
    const size_t GEMM_LDS = 147456;   // 144 KiB (3 x 48K buffers)

    gemm_cl<512, 0><<<ggrid, 512, GEMM_LDS, stream>>>(xT, wA, mid);

    irnn_fused<<<sgrid, 256, 0, stream>>>(mid, concat,
        i1_wu, i1_bu, i1_wr, i1_br, i1_wd, i1_bd, i1_wl, i1_bl);

    gemm_cl<2048, 0><<<ggrid, 512, GEMM_LDS, stream>>>(concat, wB, mid);

    irnn_fused<<<sgrid, 256, 0, stream>>>(mid, concat,
        i2_wu, i2_bu, i2_wr, i2_br, i2_wd, i2_bd, i2_wl, i2_bl);

    gemm_cl<2048, 1><<<ggrid, 512, GEMM_LDS, stream>>>(concat, wC, d_out);
}

// Round 7
// 157.616 us; speedup vs baseline: 1.0711x; 1.0711x over previous
//
#include <hip/hip_runtime.h>
#include <stdint.h>

// Geometry (fixed): B=4, C=512, H=W=64
#define NB 4
#define CB 512
#define HH 64
#define WW 64
#define HW 4096
#define C4 2048
#define PTOT (NB*HW)   // 16384 pixels across batch

typedef float  f32x4  __attribute__((ext_vector_type(4)));
typedef short  bf16x8 __attribute__((ext_vector_type(8)));

__device__ __forceinline__ float relu_f(float v){ return v > 0.f ? v : 0.f; }

__device__ __forceinline__ float bf2f(unsigned short u){
    union { uint32_t i; float f; } v; v.i = ((uint32_t)u) << 16; return v.f;
}
__device__ __forceinline__ unsigned short f2bf(float f){
    union { float f; uint32_t i; } v; v.f = f;
    uint32_t r = v.i + 0x7FFFu + ((v.i >> 16) & 1u);   // RNE
    return (unsigned short)(r >> 16);
}

__device__ __forceinline__ void gload16(const void* g, void* l){
    __builtin_amdgcn_global_load_lds(
        (const __attribute__((address_space(1))) uint32_t*)g,
        (__attribute__((address_space(3))) uint32_t*)l, 16, 0, 0);
}

// ---------------------------------------------------------------------------
// fp32 -> bf16 cast of the three weight matrices in one launch.
// ---------------------------------------------------------------------------
__global__ __launch_bounds__(256) void cast3_f32_bf16(
    const float* __restrict__ a, unsigned short* __restrict__ oa,
    const float* __restrict__ b, unsigned short* __restrict__ ob,
    const float* __restrict__ c, unsigned short* __restrict__ oc)
{
    int i = blockIdx.x * 256 + threadIdx.x;
    const float* src; unsigned short* dst; int j;
    if (i < 65536)        { src = a; dst = oa; j = i; }
    else if (i < 327680)  { src = b; dst = ob; j = i - 65536; }
    else                  { src = c; dst = oc; j = i - 327680; }
    float4 v = ((const float4*)src)[j];
    ushort4 o;
    o.x = f2bf(v.x); o.y = f2bf(v.y); o.z = f2bf(v.z); o.w = f2bf(v.w);
    ((ushort4*)dst)[j] = o;
}

// ---------------------------------------------------------------------------
// x [b][c][p] fp32  ->  xT [b*HW + p][c] bf16   (64x64 LDS tile transpose)
// ---------------------------------------------------------------------------
__global__ __launch_bounds__(256) void transpose_cast_x(
    const float* __restrict__ x, unsigned short* __restrict__ xT)
{
    __shared__ unsigned short tile[64][72];
    const int b  = blockIdx.z;
    const int p0 = blockIdx.x * 64;
    const int c0 = blockIdx.y * 64;
    const int t  = threadIdx.x;

    const int pl = (t & 15) * 4;
    const int cl = t >> 4;
    const float* src = x + ((size_t)b * CB + c0) * HW + p0;
    #pragma unroll
    for (int r = 0; r < 4; r++) {
        int c = cl + r * 16;
        float4 v = *(const float4*)(src + (size_t)c * HW + pl);
        tile[pl + 0][c] = f2bf(v.x);
        tile[pl + 1][c] = f2bf(v.y);
        tile[pl + 2][c] = f2bf(v.z);
        tile[pl + 3][c] = f2bf(v.w);
    }
    __syncthreads();
    unsigned short* dst = xT + ((size_t)b * HW + p0) * CB + c0;
    const int cl2 = (t & 15) * 4;
    const int pl2 = t >> 4;
    #pragma unroll
    for (int r = 0; r < 4; r++) {
        int p = pl2 + r * 16;
        ushort4 o = *(ushort4*)&tile[p][cl2];
        *(ushort4*)(dst + (size_t)p * CB + cl2) = o;
    }
}

// ---------------------------------------------------------------------------
// Channel-last MFMA GEMM, 4-phase/K-tile, 8 waves, double-buffer:
//   D[p][o] = sum_k A[p][k] * Bw[o][k]  (bf16 in, f32 acc)
// BM=128p x BN=256o, BK=64, 8 waves (2M x 4N), per-wave 64x64 (acc 64 VGPR).
// grid (128,2) = 256 blocks = 1/CU. LDS: 2 x (A 16K | B 32K) = 96K dynamic.
// Per tile: top {vmcnt(0); barrier} waits loads issued 4 phases earlier;
// phase 0 issues ALL 6 next-tile loads; each phase {ds_read ; barrier ;
// lgkmcnt(0) ; setprio(1) ; 8 MFMA ; setprio(0) ; barrier}.
// amdgpu_waves_per_eu(1,2): only 2 waves/EU resident (96K LDS -> 1 blk/CU);
// without this the backend assumes dyn-LDS=0, targets 8 waves/EU, caps VGPR
// at 64 and spills the accumulator (R5/R6: +129MB scratch writes/dispatch).
// OUTMODE 0: bf16 [PTOT][512] channel-last; 1: fp32 [b][512][HW] + ReLU.
// ---------------------------------------------------------------------------
template<int K, int OUTMODE>
__global__ __launch_bounds__(512) __attribute__((amdgpu_waves_per_eu(1, 2)))
void gemm_cl(
    const unsigned short* __restrict__ A,
    const unsigned short* __restrict__ Bw,
    void* __restrict__ out)
{
    extern __shared__ __align__(16) char lds[];

    const int t    = threadIdx.x;
    const int lane = t & 63;
    const int wid  = t >> 6;          // 0..7
    const int p0   = blockIdx.x * 128;
    const int o0   = blockIdx.y * 256;

    const int l15 = lane & 15;
    const int l4  = lane >> 4;        // 0..3
    const int wm  = (wid >> 2) * 64;  // wave p-offset (0,64)
    const int wn  = (wid & 3) * 64;   // wave o-offset (0..192)
    const int swz = (l15 & 7) << 4;   // read-side XOR (row&7)<<4

    f32x4 acc[4][4];
    #pragma unroll
    for (int m = 0; m < 4; m++)
        #pragma unroll
        for (int n = 0; n < 4; n++) acc[m][n] = (f32x4)0.f;

    // staging decode: 64-row chunk per (wid,j); lane -> row wid*8+sr, 16B col
    const int sr  = lane >> 3;        // 0..7
    const int scb = (lane & 7) * 16;  // byte col in 128B row
    const int skk = (scb ^ (sr << 4)) >> 1;   // pre-swizzled source k-elem off

    auto STAGE = [&](int k0, int bufo) {
        #pragma unroll
        for (int j = 0; j < 2; ++j)
            gload16(A + (size_t)(p0 + j * 64 + wid * 8 + sr) * K + k0 + skk,
                    lds + bufo + j * 8192 + wid * 1024);
        #pragma unroll
        for (int j = 0; j < 4; ++j)
            gload16(Bw + (size_t)(o0 + j * 64 + wid * 8 + sr) * K + k0 + skk,
                    lds + bufo + 16384 + j * 8192 + wid * 1024);
    };

    STAGE(0, 0);                      // tile 0 -> buf0 (6 loads in flight)
    const int NT = K / 64;

#define PH(khv, mhv, STCODE)                                                   \
    {                                                                          \
        const int colb = (khv) * 64 + l4 * 16;                                 \
        af0 = *(const bf16x8*)(lds + co + (wm + (2*(mhv)  )*16 + l15)*128 + (colb ^ swz)); \
        af1 = *(const bf16x8*)(lds + co + (wm + (2*(mhv)+1)*16 + l15)*128 + (colb ^ swz)); \
        if ((mhv) == 0) {                                                      \
            _Pragma("unroll")                                                  \
            for (int nn = 0; nn < 4; ++nn)                                     \
                bfr[nn] = *(const bf16x8*)(lds + co + 16384 +                  \
                           (wn + nn*16 + l15)*128 + (colb ^ swz));             \
        }                                                                      \
        STCODE;                                                                \
        __builtin_amdgcn_sched_barrier(0);                                     \
        __builtin_amdgcn_s_barrier();                                          \
        asm volatile("s_waitcnt lgkmcnt(0)" ::: "memory");                     \
        __builtin_amdgcn_sched_barrier(0);                                     \
        __builtin_amdgcn_s_setprio(1);                                         \
        _Pragma("unroll")                                                      \
        for (int nn = 0; nn < 4; ++nn) {                                       \
            acc[2*(mhv)  ][nn] = __builtin_amdgcn_mfma_f32_16x16x32_bf16(      \
                                    af0, bfr[nn], acc[2*(mhv)  ][nn], 0, 0, 0);\
            acc[2*(mhv)+1][nn] = __builtin_amdgcn_mfma_f32_16x16x32_bf16(      \
                                    af1, bfr[nn], acc[2*(mhv)+1][nn], 0, 0, 0);\
        }                                                                      \
        __builtin_amdgcn_s_setprio(0);                                         \
        __builtin_amdgcn_sched_barrier(0);                                     \
        __builtin_amdgcn_s_barrier();                                          \
    }

    #pragma unroll 1
    for (int tt = 0; tt < NT; ++tt) {
        const int co = (tt & 1) * 49152;        // current buffer offset
        const int no = 49152 - co;              // next buffer offset
        asm volatile("s_waitcnt vmcnt(0)" ::: "memory");  // tile tt landed
        __builtin_amdgcn_s_barrier();
        const bool st = (tt + 1 < NT);
        const int k1 = (tt + 1) * 64;
        bf16x8 bfr[4], af0, af1;

        PH(0, 0, { if (st) STAGE(k1, no); })    // phase 0: issue all 6 loads
        PH(0, 1, { })                           // phase 1
        PH(1, 0, { })                           // phase 2
        PH(1, 1, { })                           // phase 3
    }
#undef PH

    if (OUTMODE == 0) {
        unsigned short* op = (unsigned short*)out;
        #pragma unroll
        for (int m = 0; m < 4; m++)
            #pragma unroll
            for (int r = 0; r < 4; r++) {
                const int p = p0 + wm + m * 16 + l4 * 4 + r;
                #pragma unroll
                for (int n = 0; n < 4; n++) {
                    const int o = o0 + wn + n * 16 + l15;
                    op[(size_t)p * CB + o] = f2bf(acc[m][n][r]);
                }
            }
    } else {
        // fp32 channel-first + ReLU via LDS transpose, two o-halves of 128
        __syncthreads();
        float (*tl)[132] = (float(*)[132])lds;    // 128*132*4 = 67584 < 98304
        const int bb   = p0 >> 12;
        const int phw0 = p0 & (HW - 1);
        #pragma unroll
        for (int h = 0; h < 2; ++h) {
            if (((wid >> 1) & 1) == h) {
                #pragma unroll
                for (int n = 0; n < 4; n++)
                    #pragma unroll
                    for (int m = 0; m < 4; m++)
                        #pragma unroll
                        for (int r = 0; r < 4; r++)
                            tl[(wn & 127) + n * 16 + l15][wm + m * 16 + l4 * 4 + r]
                                = acc[m][n][r];
            }
            __syncthreads();
            const int orow = t >> 2;            // 0..127
            const int pseg = (t & 3) * 32;      // 0..96
            float* dst = (float*)out +
                ((size_t)(bb * CB + o0 + h * 128 + orow)) * HW + phw0 + pseg;
            #pragma unroll
            for (int j = 0; j < 8; j++) {
                float4 v = *(float4*)&tl[orow][pseg + j * 4];
                v.x = relu_f(v.x); v.y = relu_f(v.y); v.z = relu_f(v.z); v.w = relu_f(v.w);
                *(float4*)(dst + j * 4) = v;
            }
            __syncthreads();
        }
    }
}

// ---------------------------------------------------------------------------
// Fused 4-direction IRNN scan, channel-last, scalar channel per thread.
// grid (512, 4): blockIdx.y = dir (0=u,1=r,2=d,3=l). Depth-8 reg prefetch.
// ---------------------------------------------------------------------------
__global__ __launch_bounds__(256) void irnn_fused(
    const unsigned short* __restrict__ in, unsigned short* __restrict__ outc,
    const float* __restrict__ wu, const float* __restrict__ bu,
    const float* __restrict__ wr, const float* __restrict__ br,
    const float* __restrict__ wd, const float* __restrict__ bd,
    const float* __restrict__ wl, const float* __restrict__ bl)
{
    const int dir = blockIdx.y;
    const float* wv; const float* bv; int pstep, rev;
    if      (dir == 0) { wv = wu; bv = bu; pstep = 64; rev = 1; }  // up
    else if (dir == 1) { wv = wr; bv = br; pstep = 1;  rev = 0; }  // right
    else if (dir == 2) { wv = wd; bv = bd; pstep = 64; rev = 0; }  // down
    else               { wv = wl; bv = bl; pstep = 1;  rev = 1; }  // left
    const int dirOff = dir * 512;

    const int idx = blockIdx.x * 256 + threadIdx.x;  // 0..131071
    const int c = idx & 511;
    const int f = (idx >> 9) & 63;
    const int b = idx >> 15;
    const int fbase = (pstep == 64) ? f : f * 64;

    const float wc = wv[c], bc = bv[c];
    const int t0 = rev ? 63 : 0;
    const int dp = rev ? -pstep : pstep;
    const int istep = dp * CB;
    const int ostep = dp * C4;

    const unsigned short* ip = in   + ((size_t)b * HW + fbase + (size_t)t0 * pstep) * CB + c;
    unsigned short*       op = outc + ((size_t)b * HW + fbase + (size_t)t0 * pstep) * C4 + dirOff + c;

    float s = relu_f(bf2f(ip[0]));
    op[0] = 0;

    unsigned short v0 = ip[1*istep], v1 = ip[2*istep], v2 = ip[3*istep], v3 = ip[4*istep],
                   v4 = ip[5*istep], v5 = ip[6*istep], v6 = ip[7*istep], v7 = ip[8*istep];

#define DO(kk, vv) { s = relu_f(fmaf(s, wc, bc + bf2f(vv))); op[(kk)*ostep] = f2bf(s); }
    for (int g = 0; g < 6; ++g) {
        const int k0 = 1 + 8 * g;
        DO(k0+0, v0); v0 = ip[(k0+ 8)*istep];
        DO(k0+1, v1); v1 = ip[(k0+ 9)*istep];
        DO(k0+2, v2); v2 = ip[(k0+10)*istep];
        DO(k0+3, v3); v3 = ip[(k0+11)*istep];
        DO(k0+4, v4); v4 = ip[(k0+12)*istep];
        DO(k0+5, v5); v5 = ip[(k0+13)*istep];
        DO(k0+6, v6); v6 = ip[(k0+14)*istep];
        DO(k0+7, v7); v7 = ip[(k0+15)*istep];
    }
    DO(49, v0); v0 = ip[57*istep];
    DO(50, v1); v1 = ip[58*istep];
    DO(51, v2); v2 = ip[59*istep];
    DO(52, v3); v3 = ip[60*istep];
    DO(53, v4); v4 = ip[61*istep];
    DO(54, v5); v5 = ip[62*istep];
    DO(55, v6); v6 = ip[63*istep];
    DO(56, v7);
    DO(57, v0); DO(58, v1); DO(59, v2); DO(60, v3);
    DO(61, v4); DO(62, v5); DO(63, v6);
#undef DO
}

// ---------------------------------------------------------------------------
// ws map: [0,16M) xT | [16M,80M) concat_T | [80M,96M) out0/mid |
//         [96M,..) bf16 weights. conv3x3 "attention" branch is dead -> skipped.
// ---------------------------------------------------------------------------
extern "C" void kernel_launch(void* const* d_in, const int* in_sizes, int n_in,
                              void* d_out, int out_size, void* d_ws, size_t ws_size,
                              hipStream_t stream) {
    const float* x     = (const float*)d_in[0];
    const float* cin_w = (const float*)d_in[7];
    const float* c2_w  = (const float*)d_in[8];
    const float* c3_w  = (const float*)d_in[9];
    const float* i1_wu = (const float*)d_in[10];
    const float* i1_bu = (const float*)d_in[11];
    const float* i1_wr = (const float*)d_in[12];
    const float* i1_br = (const float*)d_in[13];
    const float* i1_wd = (const float*)d_in[14];
    const float* i1_bd = (const float*)d_in[15];
    const float* i1_wl = (const float*)d_in[16];
    const float* i1_bl = (const float*)d_in[17];
    const float* i2_wu = (const float*)d_in[18];
    const float* i2_bu = (const float*)d_in[19];
    const float* i2_wr = (const float*)d_in[20];
    const float* i2_br = (const float*)d_in[21];
    const float* i2_wd = (const float*)d_in[22];
    const float* i2_bd = (const float*)d_in[23];
    const float* i2_wl = (const float*)d_in[24];
    const float* i2_bl = (const float*)d_in[25];

    char* ws = (char*)d_ws;
    unsigned short* xT     = (unsigned short*)(ws);
    unsigned short* concat = (unsigned short*)(ws + (size_t)16 * 1024 * 1024);
    unsigned short* mid    = (unsigned short*)(ws + (size_t)80 * 1024 * 1024);
    unsigned short* wA     = (unsigned short*)(ws + (size_t)96 * 1024 * 1024);
    unsigned short* wB     = (unsigned short*)(wA + 512 * 512);
    unsigned short* wC     = (unsigned short*)(wB + 512 * 2048);

    cast3_f32_bf16<<<2304, 256, 0, stream>>>(cin_w, wA, c2_w, wB, c3_w, wC);
    transpose_cast_x<<<dim3(HW/64, CB/64, NB), 256, 0, stream>>>(x, xT);

    dim3 ggrid(PTOT/128, CB/256);    // 128 x 2 = 256 blocks = 1/CU
    dim3 sgrid(512, 4);
    const size_t GEMM_LDS = 98304;   // 96 KiB (2 x 48K buffers)

    gemm_cl<512, 0><<<ggrid, 512, GEMM_LDS, stream>>>(xT, wA, mid);

    irnn_fused<<<sgrid, 256, 0, stream>>>(mid, concat,
        i1_wu, i1_bu, i1_wr, i1_br, i1_wd, i1_bd, i1_wl, i1_bl);

    gemm_cl<2048, 0><<<ggrid, 512, GEMM_LDS, stream>>>(concat, wB, mid);

    irnn_fused<<<sgrid, 256, 0, stream>>>(mid, concat,
        i2_wu, i2_bu, i2_wr, i2_br, i2_wd, i2_bd, i2_wl, i2_bl);

    gemm_cl<2048, 1><<<ggrid, 512, GEMM_LDS, stream>>>(concat, wC, d_out);
}